// Round 1
// baseline (85898.370 us; speedup 1.0000x reference)
//
#include <hip/hip_runtime.h>
#include <cstdint>
#include <cstddef>

typedef unsigned int uint;
typedef __attribute__((ext_vector_type(8))) __bf16 bf16x8;
typedef __attribute__((ext_vector_type(4))) __bf16 bf16x4v;
typedef __attribute__((ext_vector_type(4))) float floatx4;

// Problem dims
#define WLD 6144      // weight row stride = 3*(D+H)
// M_ROWS = N*T = 16384, K = 1024 everywhere

// ---- workspace layout (bytes), total ~178.6 MB ----
static const size_t OFF_GATES = 0;              // bf16 16384x3072 (reused as gd)
static const size_t OFF_XB    = 100663296;      // bf16 16384x1024
static const size_t OFF_HTSEQ = 134217728;      // bf16 16384x1024
static const size_t OFF_WXTT  = 167772160;      // bf16 3072x1024 (B^T)
static const size_t OFF_WHDT  = 174063616;      // bf16 3072x1024
static const size_t OFF_WXD1T = 180355072;      // bf16 2048x1024
static const size_t OFF_WXD2T = 184549376;      // bf16 1024x1024
static const size_t OFF_HTA   = 186646528;      // f32 [1024][32] (ht transposed, dbuf A)
static const size_t OFF_HTB   = 186777600;      // f32 [1024][32]
static const size_t OFF_U     = 186908672;      // f32 [1024][32]
static const size_t OFF_RH    = 187039744;      // f32 [1024][32]
static const size_t OFF_BAR   = 187170816;      // uint[256] barrier state

__device__ __forceinline__ float sigmoidf_(float x) { return 1.f / (1.f + __expf(-x)); }
__device__ __forceinline__ float tanhf_(float x) { float e = __expf(2.f * x); return 1.f - 2.f / (e + 1.f); }

// ---------------- prep kernels ----------------

__global__ __launch_bounds__(256) void convert_x(const float4* __restrict__ x4,
                                                 __bf16* __restrict__ xb,
                                                 uint* __restrict__ bar) {
  if (blockIdx.x == 0) bar[threadIdx.x] = 0u;   // zero barrier state (ws is poisoned)
  size_t i = (size_t)blockIdx.x * 256 + threadIdx.x;   // grid sized exactly N*T*D/4
  float4 v = x4[i];
  bf16x4v o = { (__bf16)v.x, (__bf16)v.y, (__bf16)v.z, (__bf16)v.w };
  *reinterpret_cast<bf16x4v*>(xb + i * 4) = o;
}

// src: fp32 block with row stride WLD, 1024 rows (k), `gridDim.x*32` cols (c).
// dst: bf16 [c][k] (B^T layout for the MFMA GEMM).
__global__ __launch_bounds__(256) void transpose_conv(const float* __restrict__ src,
                                                      __bf16* __restrict__ dst) {
  __shared__ float t[32][33];
  const int ct = blockIdx.x, kt = blockIdx.y;
  const int j = threadIdx.x & 31, ig = threadIdx.x >> 5;
#pragma unroll
  for (int ii = 0; ii < 4; ++ii) {
    int i = ig * 4 + ii;
    t[i][j] = src[(size_t)(kt * 32 + i) * WLD + ct * 32 + j];
  }
  __syncthreads();
#pragma unroll
  for (int ii = 0; ii < 4; ++ii) {
    int cc = ig * 4 + ii;
    dst[(size_t)(ct * 32 + cc) * 1024 + kt * 32 + j] = (__bf16)t[j][cc];
  }
}

// ---------------- MFMA GEMM (A row-major bf16, B^T bf16 [n][k]) ----------------
// MODE 0: gates = A@B + bias           -> bf16 gbuf[row*3072+col]
// MODE 1: gd    = A@B + bias           -> bf16 gbuf[row*3072+col]
// MODE 2: g2 = sigmoid(gd + A@B); col<1024 -> ud, col>=1024 -> rd*x; in-place into gbuf
// MODE 3: hcd = tanh(gd[2D+col] + A@B); h = x + ud*(hcd-x) -> hout fp32
template <int MODE>
__global__ __launch_bounds__(256) void gemm_bt(const __bf16* __restrict__ A, int lda,
                                               const __bf16* __restrict__ BT,
                                               const float* __restrict__ bias,
                                               __bf16* __restrict__ gbuf,
                                               const float* __restrict__ xf,
                                               float* __restrict__ hout, int ncols) {
  __shared__ __bf16 As[128][48];   // row stride 96B (16B aligned)
  __shared__ __bf16 Bs[128][48];
  const int tid = threadIdx.x;
  const int lane = tid & 63, wave = tid >> 6;
  const int tm = blockIdx.y, tn = blockIdx.x;
  const int wm = (wave & 1) * 64, wn = (wave >> 1) * 64;
  floatx4 acc[4][4] = {};
  const int c = tid & 3, r0 = tid >> 2;
  const size_t arow = (size_t)tm * 128;
  const size_t brow = (size_t)tn * 128;

  for (int kk = 0; kk < 1024; kk += 32) {
    *reinterpret_cast<uint4*>(&As[r0][c * 8]) =
        *reinterpret_cast<const uint4*>(A + (arow + r0) * (size_t)lda + kk + c * 8);
    *reinterpret_cast<uint4*>(&As[r0 + 64][c * 8]) =
        *reinterpret_cast<const uint4*>(A + (arow + r0 + 64) * (size_t)lda + kk + c * 8);
    *reinterpret_cast<uint4*>(&Bs[r0][c * 8]) =
        *reinterpret_cast<const uint4*>(BT + (brow + r0) * 1024 + kk + c * 8);
    *reinterpret_cast<uint4*>(&Bs[r0 + 64][c * 8]) =
        *reinterpret_cast<const uint4*>(BT + (brow + r0 + 64) * 1024 + kk + c * 8);
    __syncthreads();
    const int mr = lane & 15, kg = (lane >> 4) * 8;
    bf16x8 af[4], bfr[4];
#pragma unroll
    for (int f = 0; f < 4; ++f) af[f] = *reinterpret_cast<const bf16x8*>(&As[wm + f * 16 + mr][kg]);
#pragma unroll
    for (int f = 0; f < 4; ++f) bfr[f] = *reinterpret_cast<const bf16x8*>(&Bs[wn + f * 16 + mr][kg]);
#pragma unroll
    for (int fi = 0; fi < 4; ++fi)
#pragma unroll
      for (int fj = 0; fj < 4; ++fj)
        acc[fi][fj] = __builtin_amdgcn_mfma_f32_16x16x32_bf16(af[fi], bfr[fj], acc[fi][fj], 0, 0, 0);
    __syncthreads();
  }

  // epilogue: C/D layout col=lane&15, row=(lane>>4)*4+reg
#pragma unroll
  for (int fi = 0; fi < 4; ++fi)
#pragma unroll
    for (int fj = 0; fj < 4; ++fj) {
      const int row0 = tm * 128 + wm + fi * 16 + (lane >> 4) * 4;
      const int col = tn * 128 + wn + fj * 16 + (lane & 15);
#pragma unroll
      for (int r = 0; r < 4; ++r) {
        const size_t row = (size_t)(row0 + r);
        float v = acc[fi][fj][r];
        if (MODE == 0 || MODE == 1) {
          gbuf[row * 3072 + col] = (__bf16)(v + bias[col]);
        } else if (MODE == 2) {
          float g = sigmoidf_(v + (float)gbuf[row * 3072 + col]);
          if (col < 1024)
            gbuf[row * 3072 + col] = (__bf16)g;                               // ud
          else
            gbuf[row * 3072 + col] = (__bf16)(g * xf[row * 1024 + (col - 1024)]); // rd*x
        } else {
          float hcd = tanhf_(v + (float)gbuf[row * 3072 + 2048 + col]);
          float ud = (float)gbuf[row * 3072 + col];
          float xv = xf[row * 1024 + col];
          hout[row * 1024 + col] = xv + ud * (hcd - xv);
        }
      }
    }
}

// ---------------- persistent recurrence ----------------

__device__ __forceinline__ void gbar(uint* bar) {
  __threadfence();
  __syncthreads();
  if (threadIdx.x == 0) {
    uint* sub = bar + (blockIdx.x & 7) * 16;  // 8 sub-counters, 64B apart
    uint* top = bar + 128;
    uint* gen = bar + 160;
    uint g = __hip_atomic_load(gen, __ATOMIC_RELAXED, __HIP_MEMORY_SCOPE_AGENT);
    if (__hip_atomic_fetch_add(sub, 1u, __ATOMIC_ACQ_REL, __HIP_MEMORY_SCOPE_AGENT) + 1u == 32u) {
      __hip_atomic_store(sub, 0u, __ATOMIC_RELAXED, __HIP_MEMORY_SCOPE_AGENT);
      if (__hip_atomic_fetch_add(top, 1u, __ATOMIC_ACQ_REL, __HIP_MEMORY_SCOPE_AGENT) + 1u == 8u) {
        __hip_atomic_store(top, 0u, __ATOMIC_RELAXED, __HIP_MEMORY_SCOPE_AGENT);
        __hip_atomic_store(gen, g + 1u, __ATOMIC_RELEASE, __HIP_MEMORY_SCOPE_AGENT);
      }
    }
    while (__hip_atomic_load(gen, __ATOMIC_ACQUIRE, __HIP_MEMORY_SCOPE_AGENT) == g)
      __builtin_amdgcn_s_sleep(1);
  }
  __syncthreads();
  __threadfence();
}

// 256 WGs x 256 threads, cooperative. WG b owns gg cols [b*8, b*8+8) of 2048
// and hc cols [b*4, b*4+4) of 1024; those weight columns live in LDS for all 512 steps.
// ht/u/rh buffers are [k][n] (transposed) so lane reads are coalesced.
__global__ __launch_bounds__(256) void recur_kernel(
    const __bf16* __restrict__ gates, const float* __restrict__ weight,
    const float* __restrict__ state, float* __restrict__ htA, float* __restrict__ htB,
    float* __restrict__ ubuf, float* __restrict__ rhbuf,
    __bf16* __restrict__ htseq, float* __restrict__ otail, uint* __restrict__ bar) {
  __shared__ float Wg[1024][8];   // 32 KB: Whtg columns b*8..b*8+7
  __shared__ float Wc[1024][4];   // 16 KB: Whtc columns b*4..b*4+3
  __shared__ float partial[256];
  const int b = blockIdx.x, tid = threadIdx.x;

  for (int idx = tid; idx < 8192; idx += 256) {
    int k = idx >> 3, j = idx & 7;
    Wg[k][j] = weight[(size_t)(1024 + k) * WLD + b * 8 + j];
  }
  for (int idx = tid; idx < 4096; idx += 256) {
    int k = idx >> 2, j = idx & 3;
    Wc[k][j] = weight[(size_t)(1024 + k) * WLD + 2048 + b * 4 + j];
  }
  if (b < 32) {  // init ht (transposed) from state
    for (int idx = tid; idx < 1024; idx += 256) {
      int kk = b * 32 + (idx >> 5), nn = idx & 31;
      htA[kk * 32 + nn] = state[nn * 1024 + kk];
    }
  }
  gbar(bar);

  float* hprev = htA;
  float* hnext = htB;
  const int n = tid & 31, jg = tid >> 5;  // phase A: one (n, col) per thread
  const int gcol = b * 8 + jg;

  for (int t = 0; t < 512; ++t) {
    // ---- phase A: gg = sigmoid(gates + ht @ Whtg) ----
    {
      float acc = (float)gates[((size_t)n * 512 + t) * 3072 + gcol];
#pragma unroll 8
      for (int k = 0; k < 1024; ++k) acc += hprev[k * 32 + n] * Wg[k][jg];
      float gg = sigmoidf_(acc);
      if (gcol < 1024)
        ubuf[gcol * 32 + n] = gg;                                   // u
      else
        rhbuf[(gcol - 1024) * 32 + n] = gg * hprev[(gcol - 1024) * 32 + n];  // r*ht
    }
    gbar(bar);
    // ---- phase B: hc = tanh(gates_c + (r*ht) @ Whtc); ht update ----
    {
      const int half = tid >> 7, i2 = tid & 127, n2 = i2 & 31, j2 = i2 >> 5;
      const int ccol = b * 4 + j2;
      float acc = 0.f;
      const int kbeg = half * 512, kend = kbeg + 512;
#pragma unroll 8
      for (int k = kbeg; k < kend; ++k) acc += rhbuf[k * 32 + n2] * Wc[k][j2];
      partial[tid] = acc;
      __syncthreads();
      if (tid < 128) {
        float a = partial[tid] + partial[tid + 128] +
                  (float)gates[((size_t)n2 * 512 + t) * 3072 + 2048 + ccol];
        float hc = tanhf_(a);
        float hp = hprev[ccol * 32 + n2];
        float up = ubuf[ccol * 32 + n2];
        float hn = hp + up * (hc - hp);
        hnext[ccol * 32 + n2] = hn;
        htseq[((size_t)n2 * 512 + t) * 1024 + ccol] = (__bf16)hn;
        if (t == 511) otail[n2 * 1024 + ccol] = hn;   // final_ht (fp32)
      }
    }
    gbar(bar);
    float* tmp = hprev; hprev = hnext; hnext = tmp;
  }
}

// ---------------- launch ----------------

extern "C" void kernel_launch(void* const* d_in, const int* in_sizes, int n_in,
                              void* d_out, int out_size, void* d_ws, size_t ws_size,
                              hipStream_t stream) {
  const float* x = (const float*)d_in[0];
  const float* state = (const float*)d_in[1];
  const float* weight = (const float*)d_in[2];
  const float* bias = (const float*)d_in[3];
  float* out = (float*)d_out;
  char* ws = (char*)d_ws;

  __bf16* gates = (__bf16*)(ws + OFF_GATES);
  __bf16* xb    = (__bf16*)(ws + OFF_XB);
  __bf16* htseq = (__bf16*)(ws + OFF_HTSEQ);
  __bf16* wxtt  = (__bf16*)(ws + OFF_WXTT);
  __bf16* whdt  = (__bf16*)(ws + OFF_WHDT);
  __bf16* wxd1t = (__bf16*)(ws + OFF_WXD1T);
  __bf16* wxd2t = (__bf16*)(ws + OFF_WXD2T);
  float* htA   = (float*)(ws + OFF_HTA);
  float* htB   = (float*)(ws + OFF_HTB);
  float* ubuf  = (float*)(ws + OFF_U);
  float* rhbuf = (float*)(ws + OFF_RH);
  uint* bar    = (uint*)(ws + OFF_BAR);

  // prep: x -> bf16 (+ zero barrier), weight blocks -> bf16 B^T
  hipLaunchKernelGGL(convert_x, dim3(16384), dim3(256), 0, stream, (const float4*)x, xb, bar);
  hipLaunchKernelGGL(transpose_conv, dim3(96, 32), dim3(256), 0, stream, weight, wxtt);
  hipLaunchKernelGGL(transpose_conv, dim3(64, 32), dim3(256), 0, stream, weight + 3072, wxd1t);
  hipLaunchKernelGGL(transpose_conv, dim3(32, 32), dim3(256), 0, stream, weight + 5120, wxd2t);
  hipLaunchKernelGGL(transpose_conv, dim3(96, 32), dim3(256), 0, stream,
                     weight + (size_t)1024 * WLD + 3072, whdt);

  // gates = x @ Wxt + bias[:3H]
  hipLaunchKernelGGL((gemm_bt<0>), dim3(24, 128), dim3(256), 0, stream,
                     xb, 1024, wxtt, bias, gates, (const float*)nullptr, (float*)nullptr, 3072);

  // recurrence (cooperative, persistent)
  {
    const __bf16* gatesc = gates;
    float* otail = out + 16777216;
    void* args[10];
    args[0] = (void*)&gatesc; args[1] = (void*)&weight; args[2] = (void*)&state;
    args[3] = (void*)&htA;    args[4] = (void*)&htB;    args[5] = (void*)&ubuf;
    args[6] = (void*)&rhbuf;  args[7] = (void*)&htseq;  args[8] = (void*)&otail;
    args[9] = (void*)&bar;
    hipLaunchCooperativeKernel(recur_kernel, dim3(256), dim3(256), args, 0, stream);
  }

  // gd = ht_seq @ Whd + bias[3H:]  (into gates buffer)
  hipLaunchKernelGGL((gemm_bt<1>), dim3(24, 128), dim3(256), 0, stream,
                     htseq, 1024, whdt, bias + 3072, gates, (const float*)nullptr,
                     (float*)nullptr, 3072);
  // g2 = sigmoid(gd[:, :2D] + x @ Wxd[:, :2D]); ud/rx in-place
  hipLaunchKernelGGL((gemm_bt<2>), dim3(16, 128), dim3(256), 0, stream,
                     xb, 1024, wxd1t, bias, gates, x, (float*)nullptr, 2048);
  // hcd = tanh(gd[:, 2D:] + rx @ Wxd[:, 2D:]); h = x + ud*(hcd - x)
  hipLaunchKernelGGL((gemm_bt<3>), dim3(8, 128), dim3(256), 0, stream,
                     gates + 1024, 3072, wxd2t, bias, gates, x, out, 1024);
}

// Round 2
// 33540.594 us; speedup vs baseline: 2.5610x; 2.5610x over previous
//
#include <hip/hip_runtime.h>
#include <cstdint>
#include <cstddef>

typedef unsigned int uint;
typedef __attribute__((ext_vector_type(8))) __bf16 bf16x8;
typedef __attribute__((ext_vector_type(4))) __bf16 bf16x4v;
typedef __attribute__((ext_vector_type(4))) float floatx4;

#define WLD 6144      // weight row stride = 3*(D+H)

// ---- workspace layout (bytes). Row convention for xb/gates/htseq: r = t*32 + n (t-major).
static const size_t OFF_GATES = 0;              // bf16 16384x3072
static const size_t OFF_XB    = 100663296;      // bf16 16384x1024
static const size_t OFF_HTSEQ = 134217728;      // bf16 16384x1024
// whtg_t/whtc_t overlay the htseq region: consumed (into LDS) before any htseq write.
static const size_t OFF_WHTGT = OFF_HTSEQ;              // bf16 2048x1024
static const size_t OFF_WHTCT = OFF_HTSEQ + 4194304;    // bf16 1024x1024
static const size_t OFF_WXTT  = 167772160;      // bf16 3072x1024 (B^T)
static const size_t OFF_WHDT  = 174063616;      // bf16 3072x1024
static const size_t OFF_WXD1T = 180355072;      // bf16 2048x1024
static const size_t OFF_WXD2T = 184549376;      // bf16 1024x1024
static const size_t OFF_HTG   = 186646528;      // bf16 32x1024 (ht broadcast)
static const size_t OFF_RHG   = 186712064;      // bf16 32x1024 (r*ht broadcast)
static const size_t OFF_BAR   = 186777600;      // uint[512]

__device__ __forceinline__ float sigmoidf_(float x) { return 1.f / (1.f + __expf(-x)); }
__device__ __forceinline__ float tanhf_(float x) { float e = __expf(2.f * x); return 1.f - 2.f / (e + 1.f); }

// ---------------- prep kernels ----------------

// x [n][t][1024] fp32 -> xb bf16 rows r=t*32+n. Also zeroes barrier state.
__global__ __launch_bounds__(256) void convert_x(const float4* __restrict__ x4,
                                                 __bf16* __restrict__ xb,
                                                 uint* __restrict__ bar) {
  if (blockIdx.x == 0) { bar[threadIdx.x] = 0u; bar[256 + threadIdx.x] = 0u; }
  const int s = blockIdx.x;              // source row n*512+t
  const int n = s >> 9, t = s & 511;
  const int d = (t << 5) | n;            // dest row t*32+n
  float4 v = x4[(size_t)s * 256 + threadIdx.x];
  bf16x4v o = { (__bf16)v.x, (__bf16)v.y, (__bf16)v.z, (__bf16)v.w };
  *reinterpret_cast<bf16x4v*>(xb + (size_t)d * 1024 + threadIdx.x * 4) = o;
}

// src: fp32 block, row stride WLD, 1024 rows (k), gridDim.x*32 cols. dst: bf16 [c][k].
__global__ __launch_bounds__(256) void transpose_conv(const float* __restrict__ src,
                                                      __bf16* __restrict__ dst) {
  __shared__ float t[32][33];
  const int ct = blockIdx.x, kt = blockIdx.y;
  const int j = threadIdx.x & 31, ig = threadIdx.x >> 5;
#pragma unroll
  for (int ii = 0; ii < 4; ++ii) {
    int i = ig * 4 + ii;
    t[i][j] = src[(size_t)(kt * 32 + i) * WLD + ct * 32 + j];
  }
  __syncthreads();
#pragma unroll
  for (int ii = 0; ii < 4; ++ii) {
    int cc = ig * 4 + ii;
    dst[(size_t)(ct * 32 + cc) * 1024 + kt * 32 + j] = (__bf16)t[j][cc];
  }
}

// ---------------- MFMA GEMM (A row-major bf16 t-major rows, B^T bf16 [n][k]) ----------------
template <int MODE>
__global__ __launch_bounds__(256) void gemm_bt(const __bf16* __restrict__ A, int lda,
                                               const __bf16* __restrict__ BT,
                                               const float* __restrict__ bias,
                                               __bf16* __restrict__ gbuf,
                                               const float* __restrict__ xf,
                                               float* __restrict__ hout, int ncols) {
  __shared__ __bf16 As[128][48];
  __shared__ __bf16 Bs[128][48];
  const int tid = threadIdx.x;
  const int lane = tid & 63, wave = tid >> 6;
  const int tm = blockIdx.y, tn = blockIdx.x;
  const int wm = (wave & 1) * 64, wn = (wave >> 1) * 64;
  floatx4 acc[4][4] = {};
  const int c = tid & 3, r0 = tid >> 2;
  const size_t arow = (size_t)tm * 128;
  const size_t brow = (size_t)tn * 128;

  for (int kk = 0; kk < 1024; kk += 32) {
    *reinterpret_cast<uint4*>(&As[r0][c * 8]) =
        *reinterpret_cast<const uint4*>(A + (arow + r0) * (size_t)lda + kk + c * 8);
    *reinterpret_cast<uint4*>(&As[r0 + 64][c * 8]) =
        *reinterpret_cast<const uint4*>(A + (arow + r0 + 64) * (size_t)lda + kk + c * 8);
    *reinterpret_cast<uint4*>(&Bs[r0][c * 8]) =
        *reinterpret_cast<const uint4*>(BT + (brow + r0) * 1024 + kk + c * 8);
    *reinterpret_cast<uint4*>(&Bs[r0 + 64][c * 8]) =
        *reinterpret_cast<const uint4*>(BT + (brow + r0 + 64) * 1024 + kk + c * 8);
    __syncthreads();
    const int mr = lane & 15, kg = (lane >> 4) * 8;
    bf16x8 af[4], bfr[4];
#pragma unroll
    for (int f = 0; f < 4; ++f) af[f] = *reinterpret_cast<const bf16x8*>(&As[wm + f * 16 + mr][kg]);
#pragma unroll
    for (int f = 0; f < 4; ++f) bfr[f] = *reinterpret_cast<const bf16x8*>(&Bs[wn + f * 16 + mr][kg]);
#pragma unroll
    for (int fi = 0; fi < 4; ++fi)
#pragma unroll
      for (int fj = 0; fj < 4; ++fj)
        acc[fi][fj] = __builtin_amdgcn_mfma_f32_16x16x32_bf16(af[fi], bfr[fj], acc[fi][fj], 0, 0, 0);
    __syncthreads();
  }

#pragma unroll
  for (int fi = 0; fi < 4; ++fi)
#pragma unroll
    for (int fj = 0; fj < 4; ++fj) {
      const int row0 = tm * 128 + wm + fi * 16 + (lane >> 4) * 4;
      const int col = tn * 128 + wn + fj * 16 + (lane & 15);
#pragma unroll
      for (int r = 0; r < 4; ++r) {
        const size_t row = (size_t)(row0 + r);
        float v = acc[fi][fj][r];
        if (MODE == 0 || MODE == 1) {
          gbuf[row * 3072 + col] = (__bf16)(v + bias[col]);
        } else if (MODE == 2) {
          float g = sigmoidf_(v + (float)gbuf[row * 3072 + col]);
          const size_t xrow = (size_t)(row & 31) * 512 + (row >> 5);
          if (col < 1024)
            gbuf[row * 3072 + col] = (__bf16)g;                                   // ud
          else
            gbuf[row * 3072 + col] = (__bf16)(g * xf[xrow * 1024 + (col - 1024)]); // rd*x
        } else {
          float hcd = tanhf_(v + (float)gbuf[row * 3072 + 2048 + col]);
          float ud = (float)gbuf[row * 3072 + col];
          const size_t xrow = (size_t)(row & 31) * 512 + (row >> 5);
          float xv = xf[xrow * 1024 + col];
          hout[xrow * 1024 + col] = xv + ud * (hcd - xv);
        }
      }
    }
}

// ---------------- persistent recurrence ----------------

__device__ __forceinline__ void gbar(uint* bar) {
  __threadfence();
  __syncthreads();
  if (threadIdx.x == 0) {
    uint* sub = bar + (blockIdx.x & 15) * 16;   // 16 sub-counters, 64B apart
    uint* top = bar + 256;
    uint* gen = bar + 272;
    uint g = __hip_atomic_load(gen, __ATOMIC_RELAXED, __HIP_MEMORY_SCOPE_AGENT);
    if (__hip_atomic_fetch_add(sub, 1u, __ATOMIC_ACQ_REL, __HIP_MEMORY_SCOPE_AGENT) + 1u == 8u) {
      __hip_atomic_store(sub, 0u, __ATOMIC_RELAXED, __HIP_MEMORY_SCOPE_AGENT);
      if (__hip_atomic_fetch_add(top, 1u, __ATOMIC_ACQ_REL, __HIP_MEMORY_SCOPE_AGENT) + 1u == 16u) {
        __hip_atomic_store(top, 0u, __ATOMIC_RELAXED, __HIP_MEMORY_SCOPE_AGENT);
        __hip_atomic_store(gen, g + 1u, __ATOMIC_RELEASE, __HIP_MEMORY_SCOPE_AGENT);
      }
    }
    while (__hip_atomic_load(gen, __ATOMIC_ACQUIRE, __HIP_MEMORY_SCOPE_AGENT) == g)
      __builtin_amdgcn_s_sleep(1);
  }
  __syncthreads();
  __threadfence();
}

// 128 WGs x 256 threads. WG b owns gg cols {8b..8b+7} u {1024+8b..1024+8b+7} and hc cols {8b..8b+7}.
// Weights bf16 in LDS for all 512 steps. Per phase: bulk-copy broadcast vector (64KB bf16) to LDS,
// MFMA (K split over 4 waves), LDS reduce, epilogue. ht master fp32 in LDS (hp_s), never re-read.
#define SMEM_BYTES 128896
__global__ __launch_bounds__(256) void recur_kernel(
    const __bf16* __restrict__ gates, const float* __restrict__ state,
    const __bf16* __restrict__ whtg_t, const __bf16* __restrict__ whtc_t,
    __bf16* __restrict__ ht_g, __bf16* __restrict__ rh_g,
    __bf16* __restrict__ htseq, float* __restrict__ otail, uint* __restrict__ bar) {
  extern __shared__ char smem[];
  __bf16* htb = (__bf16*)smem;                   // [32][1032]  66048 B
  __bf16* Wg  = (__bf16*)(smem + 66048);         // [16][1032]  33024 B
  __bf16* Wc  = (__bf16*)(smem + 99072);         // [8][1032]   16512 B
  float* red  = (float*)(smem + 115584);         // [4][32][16]  8192 B
  float* gg_s = (float*)(smem + 123776);         // [32][16]     2048 B
  float* u_s  = (float*)(smem + 125824);         // [32][8]      1024 B
  float* hp_s = (float*)(smem + 126848);         // [32][8]      1024 B
  float* hn_s = (float*)(smem + 127872);         // [32][8]      1024 B

  const int b = blockIdx.x, tid = threadIdx.x;
  const int lane = tid & 63, w = tid >> 6;
  const int mr = lane & 15, kq = lane >> 4;
  const int nn = tid & 31, j = tid >> 5;          // reduce mapping
  const int rn = tid >> 3, rj = tid & 7;          // remap mapping (16B segments)

  // ---- init: weights -> LDS (bf16, padded stride 1032), hp fp32, ht_g bf16 ----
  for (int idx = tid; idx < 2048; idx += 256) {
    int row = idx >> 7, seg = idx & 127;
    int src = (row < 8) ? (b * 8 + row) : (1024 + b * 8 + row - 8);
    *reinterpret_cast<uint4*>(Wg + row * 1032 + seg * 8) =
        *reinterpret_cast<const uint4*>(whtg_t + (size_t)src * 1024 + seg * 8);
  }
  for (int idx = tid; idx < 1024; idx += 256) {
    int row = idx >> 7, seg = idx & 127;
    *reinterpret_cast<uint4*>(Wc + row * 1032 + seg * 8) =
        *reinterpret_cast<const uint4*>(whtc_t + (size_t)(b * 8 + row) * 1024 + seg * 8);
  }
  {
    float sv = state[rn * 1024 + b * 8 + rj];
    hp_s[rn * 8 + rj] = sv;
    ht_g[rn * 1024 + b * 8 + rj] = (__bf16)sv;
  }
  gbar(bar);

  for (int t = 0; t < 512; ++t) {
    // ================= phase A: gg = sigmoid(gates + ht @ Whtg) =================
    {
      uint4 tmp[16];
      const uint4* src = reinterpret_cast<const uint4*>(ht_g + rn * 1024 + rj * 128);
#pragma unroll
      for (int i = 0; i < 16; ++i) tmp[i] = src[i];
      const size_t grow = (size_t)(t * 32 + nn) * 3072 + b * 8;
      float g0 = (float)gates[grow + j];
      float g1 = (float)gates[grow + 1024 + j];
      uint4* dst = reinterpret_cast<uint4*>(htb + rn * 1032 + rj * 128);
#pragma unroll
      for (int i = 0; i < 16; ++i) dst[i] = tmp[i];
      __syncthreads();

      floatx4 acc0 = {0.f, 0.f, 0.f, 0.f}, acc1 = {0.f, 0.f, 0.f, 0.f};
#pragma unroll
      for (int c8 = 0; c8 < 8; ++c8) {
        int kb = w * 256 + c8 * 32 + kq * 8;
        bf16x8 a0 = *reinterpret_cast<const bf16x8*>(htb + mr * 1032 + kb);
        bf16x8 a1 = *reinterpret_cast<const bf16x8*>(htb + (16 + mr) * 1032 + kb);
        bf16x8 bb = *reinterpret_cast<const bf16x8*>(Wg + mr * 1032 + kb);
        acc0 = __builtin_amdgcn_mfma_f32_16x16x32_bf16(a0, bb, acc0, 0, 0, 0);
        acc1 = __builtin_amdgcn_mfma_f32_16x16x32_bf16(a1, bb, acc1, 0, 0, 0);
      }
#pragma unroll
      for (int r = 0; r < 4; ++r) {
        red[w * 512 + (kq * 4 + r) * 16 + mr] = acc0[r];
        red[w * 512 + (16 + kq * 4 + r) * 16 + mr] = acc1[r];
      }
      __syncthreads();
      float s0 = red[nn * 16 + j] + red[512 + nn * 16 + j] +
                 red[1024 + nn * 16 + j] + red[1536 + nn * 16 + j];
      float s1 = red[nn * 16 + j + 8] + red[512 + nn * 16 + j + 8] +
                 red[1024 + nn * 16 + j + 8] + red[1536 + nn * 16 + j + 8];
      gg_s[nn * 16 + j] = sigmoidf_(s0 + g0);
      gg_s[nn * 16 + j + 8] = sigmoidf_(s1 + g1);
      __syncthreads();
      u_s[rn * 8 + rj] = gg_s[rn * 16 + rj];
      float rr = gg_s[rn * 16 + 8 + rj];
      float hv = (float)htb[rn * 1032 + b * 8 + rj];
      rh_g[rn * 1024 + b * 8 + rj] = (__bf16)(rr * hv);
    }
    gbar(bar);
    // ================= phase B: hc = tanh(gates_c + (r*ht) @ Whtc); update =================
    {
      uint4 tmp[16];
      const uint4* src = reinterpret_cast<const uint4*>(rh_g + rn * 1024 + rj * 128);
#pragma unroll
      for (int i = 0; i < 16; ++i) tmp[i] = src[i];
      float gc = (float)gates[(size_t)(t * 32 + nn) * 3072 + 2048 + b * 8 + j];
      uint4* dst = reinterpret_cast<uint4*>(htb + rn * 1032 + rj * 128);
#pragma unroll
      for (int i = 0; i < 16; ++i) dst[i] = tmp[i];
      __syncthreads();

      floatx4 acc0 = {0.f, 0.f, 0.f, 0.f}, acc1 = {0.f, 0.f, 0.f, 0.f};
#pragma unroll
      for (int c8 = 0; c8 < 8; ++c8) {
        int kb = w * 256 + c8 * 32 + kq * 8;
        bf16x8 a0 = *reinterpret_cast<const bf16x8*>(htb + mr * 1032 + kb);
        bf16x8 a1 = *reinterpret_cast<const bf16x8*>(htb + (16 + mr) * 1032 + kb);
        bf16x8 bb = *reinterpret_cast<const bf16x8*>(Wc + (mr & 7) * 1032 + kb);
        acc0 = __builtin_amdgcn_mfma_f32_16x16x32_bf16(a0, bb, acc0, 0, 0, 0);
        acc1 = __builtin_amdgcn_mfma_f32_16x16x32_bf16(a1, bb, acc1, 0, 0, 0);
      }
#pragma unroll
      for (int r = 0; r < 4; ++r) {
        red[w * 512 + (kq * 4 + r) * 16 + mr] = acc0[r];
        red[w * 512 + (16 + kq * 4 + r) * 16 + mr] = acc1[r];
      }
      __syncthreads();
      float s = red[nn * 16 + j] + red[512 + nn * 16 + j] +
                red[1024 + nn * 16 + j] + red[1536 + nn * 16 + j];
      float hc = tanhf_(s + gc);
      float hp = hp_s[nn * 8 + j];
      float uu = u_s[nn * 8 + j];
      float hn = hp + uu * (hc - hp);
      hp_s[nn * 8 + j] = hn;
      hn_s[nn * 8 + j] = hn;
      __syncthreads();
      float v = hn_s[rn * 8 + rj];
      ht_g[rn * 1024 + b * 8 + rj] = (__bf16)v;
      htseq[(size_t)(t * 32 + rn) * 1024 + b * 8 + rj] = (__bf16)v;
      if (t == 511) otail[rn * 1024 + b * 8 + rj] = v;
    }
    gbar(bar);
  }
}

// ---------------- launch ----------------

extern "C" void kernel_launch(void* const* d_in, const int* in_sizes, int n_in,
                              void* d_out, int out_size, void* d_ws, size_t ws_size,
                              hipStream_t stream) {
  const float* x = (const float*)d_in[0];
  const float* state = (const float*)d_in[1];
  const float* weight = (const float*)d_in[2];
  const float* bias = (const float*)d_in[3];
  float* out = (float*)d_out;
  char* ws = (char*)d_ws;

  __bf16* gates  = (__bf16*)(ws + OFF_GATES);
  __bf16* xb     = (__bf16*)(ws + OFF_XB);
  __bf16* htseq  = (__bf16*)(ws + OFF_HTSEQ);
  __bf16* whtg_t = (__bf16*)(ws + OFF_WHTGT);
  __bf16* whtc_t = (__bf16*)(ws + OFF_WHTCT);
  __bf16* wxtt   = (__bf16*)(ws + OFF_WXTT);
  __bf16* whdt   = (__bf16*)(ws + OFF_WHDT);
  __bf16* wxd1t  = (__bf16*)(ws + OFF_WXD1T);
  __bf16* wxd2t  = (__bf16*)(ws + OFF_WXD2T);
  __bf16* ht_g   = (__bf16*)(ws + OFF_HTG);
  __bf16* rh_g   = (__bf16*)(ws + OFF_RHG);
  uint*   bar    = (uint*)(ws + OFF_BAR);

  // prep: x -> bf16 t-major (+ zero barrier), weight blocks -> bf16 B^T
  hipLaunchKernelGGL(convert_x, dim3(16384), dim3(256), 0, stream, (const float4*)x, xb, bar);
  hipLaunchKernelGGL(transpose_conv, dim3(96, 32), dim3(256), 0, stream, weight, wxtt);
  hipLaunchKernelGGL(transpose_conv, dim3(64, 32), dim3(256), 0, stream, weight + 3072, wxd1t);
  hipLaunchKernelGGL(transpose_conv, dim3(32, 32), dim3(256), 0, stream, weight + 5120, wxd2t);
  hipLaunchKernelGGL(transpose_conv, dim3(96, 32), dim3(256), 0, stream,
                     weight + (size_t)1024 * WLD + 3072, whdt);
  hipLaunchKernelGGL(transpose_conv, dim3(64, 32), dim3(256), 0, stream,
                     weight + (size_t)1024 * WLD, whtg_t);
  hipLaunchKernelGGL(transpose_conv, dim3(32, 32), dim3(256), 0, stream,
                     weight + (size_t)1024 * WLD + 2048, whtc_t);

  // gates = x @ Wxt + bias[:3H]   (t-major rows)
  hipLaunchKernelGGL((gemm_bt<0>), dim3(24, 128), dim3(256), 0, stream,
                     xb, 1024, wxtt, bias, gates, (const float*)nullptr, (float*)nullptr, 3072);

  // recurrence (cooperative, 128 WGs, 129KB dynamic LDS)
  {
    (void)hipFuncSetAttribute(reinterpret_cast<const void*>(recur_kernel),
                              hipFuncAttributeMaxDynamicSharedMemorySize, SMEM_BYTES);
    const __bf16* gatesc = gates;
    float* otail = out + 16777216;
    void* args[9];
    args[0] = (void*)&gatesc; args[1] = (void*)&state;  args[2] = (void*)&whtg_t;
    args[3] = (void*)&whtc_t; args[4] = (void*)&ht_g;   args[5] = (void*)&rh_g;
    args[6] = (void*)&htseq;  args[7] = (void*)&otail;  args[8] = (void*)&bar;
    hipLaunchCooperativeKernel(recur_kernel, dim3(128), dim3(256), args, SMEM_BYTES, stream);
  }

  // gd = ht_seq @ Whd + bias[3H:]  (into gates buffer)
  hipLaunchKernelGGL((gemm_bt<1>), dim3(24, 128), dim3(256), 0, stream,
                     htseq, 1024, whdt, bias + 3072, gates, (const float*)nullptr,
                     (float*)nullptr, 3072);
  // g2 = sigmoid(gd[:, :2D] + x @ Wxd[:, :2D]); ud/rx in-place
  hipLaunchKernelGGL((gemm_bt<2>), dim3(16, 128), dim3(256), 0, stream,
                     xb, 1024, wxd1t, bias, gates, x, (float*)nullptr, 2048);
  // hcd = tanh(gd[:, 2D:] + rx @ Wxd[:, 2D:]); h = x + ud*(hcd - x)
  hipLaunchKernelGGL((gemm_bt<3>), dim3(8, 128), dim3(256), 0, stream,
                     gates + 1024, 3072, wxd2t, bias, gates, x, out, 1024);
}

// Round 3
// 7333.060 us; speedup vs baseline: 11.7139x; 4.5739x over previous
//
#include <hip/hip_runtime.h>
#include <cstdint>
#include <cstddef>

typedef unsigned int uint;
typedef unsigned long long u64;
typedef __attribute__((ext_vector_type(8))) __bf16 bf16x8;
typedef __attribute__((ext_vector_type(4))) __bf16 bf16x4v;
typedef __attribute__((ext_vector_type(4))) float floatx4;

#define WLD 6144      // weight row stride = 3*(D+H)

// ---- workspace layout (bytes). Row convention for xb/gates/htseq: r = t*32 + n (t-major).
static const size_t OFF_GATES = 0;              // bf16 16384x3072
static const size_t OFF_XB    = 100663296;      // bf16 16384x1024
static const size_t OFF_HTSEQ = 134217728;      // bf16 16384x1024
// whtg_t/whtc_t overlay the htseq region: consumed (into LDS) before any htseq write.
static const size_t OFF_WHTGT = OFF_HTSEQ;              // bf16 2048x1024
static const size_t OFF_WHTCT = OFF_HTSEQ + 4194304;    // bf16 1024x1024
static const size_t OFF_WXTT  = 167772160;      // bf16 3072x1024 (B^T)
static const size_t OFF_WHDT  = 174063616;      // bf16 3072x1024
static const size_t OFF_WXD1T = 180355072;      // bf16 2048x1024
static const size_t OFF_WXD2T = 184549376;      // bf16 1024x1024
static const size_t OFF_HTG   = 186646528;      // bf16 32x1024 (ht broadcast, LIC-coherent)
static const size_t OFF_RHG   = 186712064;      // bf16 32x1024 (r*ht broadcast)
static const size_t OFF_BAR   = 186777600;      // uint[512]

__device__ __forceinline__ float sigmoidf_(float x) { return 1.f / (1.f + __expf(-x)); }
__device__ __forceinline__ float tanhf_(float x) { float e = __expf(2.f * x); return 1.f - 2.f / (e + 1.f); }

// agent-scope relaxed atomics: global_load/store_dwordx2 with coherence bits —
// operate at LIC (device coherence point), no buffer_wbl2 / buffer_inv emitted.
__device__ __forceinline__ u64 ald(const __bf16* p) {
  return __hip_atomic_load((const u64*)p, __ATOMIC_RELAXED, __HIP_MEMORY_SCOPE_AGENT);
}
__device__ __forceinline__ void ast(__bf16* p, u64 v) {
  __hip_atomic_store((u64*)p, v, __ATOMIC_RELAXED, __HIP_MEMORY_SCOPE_AGENT);
}
union B8 { u64 u[2]; bf16x8 v; };

// ---------------- prep kernels ----------------

// x [n][t][1024] fp32 -> xb bf16 rows r=t*32+n. Also zeroes barrier state (atomically,
// so the zeros live at the coherence point, not dirty in one XCD's L2).
__global__ __launch_bounds__(256) void convert_x(const float4* __restrict__ x4,
                                                 __bf16* __restrict__ xb,
                                                 uint* __restrict__ bar) {
  if (blockIdx.x == 0) {
    __hip_atomic_store(bar + threadIdx.x, 0u, __ATOMIC_RELAXED, __HIP_MEMORY_SCOPE_AGENT);
    __hip_atomic_store(bar + 256 + threadIdx.x, 0u, __ATOMIC_RELAXED, __HIP_MEMORY_SCOPE_AGENT);
  }
  const int s = blockIdx.x;              // source row n*512+t
  const int n = s >> 9, t = s & 511;
  const int d = (t << 5) | n;            // dest row t*32+n
  float4 v = x4[(size_t)s * 256 + threadIdx.x];
  bf16x4v o = { (__bf16)v.x, (__bf16)v.y, (__bf16)v.z, (__bf16)v.w };
  *reinterpret_cast<bf16x4v*>(xb + (size_t)d * 1024 + threadIdx.x * 4) = o;
}

// src: fp32 block, row stride WLD, 1024 rows (k), gridDim.x*32 cols. dst: bf16 [c][k].
__global__ __launch_bounds__(256) void transpose_conv(const float* __restrict__ src,
                                                      __bf16* __restrict__ dst) {
  __shared__ float t[32][33];
  const int ct = blockIdx.x, kt = blockIdx.y;
  const int j = threadIdx.x & 31, ig = threadIdx.x >> 5;
#pragma unroll
  for (int ii = 0; ii < 4; ++ii) {
    int i = ig * 4 + ii;
    t[i][j] = src[(size_t)(kt * 32 + i) * WLD + ct * 32 + j];
  }
  __syncthreads();
#pragma unroll
  for (int ii = 0; ii < 4; ++ii) {
    int cc = ig * 4 + ii;
    dst[(size_t)(ct * 32 + cc) * 1024 + kt * 32 + j] = (__bf16)t[j][cc];
  }
}

// ---------------- MFMA GEMM (A row-major bf16 t-major rows, B^T bf16 [n][k]) ----------------
template <int MODE>
__global__ __launch_bounds__(256) void gemm_bt(const __bf16* __restrict__ A, int lda,
                                               const __bf16* __restrict__ BT,
                                               const float* __restrict__ bias,
                                               __bf16* __restrict__ gbuf,
                                               const float* __restrict__ xf,
                                               float* __restrict__ hout, int ncols) {
  __shared__ __bf16 As[128][48];
  __shared__ __bf16 Bs[128][48];
  const int tid = threadIdx.x;
  const int lane = tid & 63, wave = tid >> 6;
  const int tm = blockIdx.y, tn = blockIdx.x;
  const int wm = (wave & 1) * 64, wn = (wave >> 1) * 64;
  floatx4 acc[4][4] = {};
  const int c = tid & 3, r0 = tid >> 2;
  const size_t arow = (size_t)tm * 128;
  const size_t brow = (size_t)tn * 128;

  for (int kk = 0; kk < 1024; kk += 32) {
    *reinterpret_cast<uint4*>(&As[r0][c * 8]) =
        *reinterpret_cast<const uint4*>(A + (arow + r0) * (size_t)lda + kk + c * 8);
    *reinterpret_cast<uint4*>(&As[r0 + 64][c * 8]) =
        *reinterpret_cast<const uint4*>(A + (arow + r0 + 64) * (size_t)lda + kk + c * 8);
    *reinterpret_cast<uint4*>(&Bs[r0][c * 8]) =
        *reinterpret_cast<const uint4*>(BT + (brow + r0) * 1024 + kk + c * 8);
    *reinterpret_cast<uint4*>(&Bs[r0 + 64][c * 8]) =
        *reinterpret_cast<const uint4*>(BT + (brow + r0 + 64) * 1024 + kk + c * 8);
    __syncthreads();
    const int mr = lane & 15, kg = (lane >> 4) * 8;
    bf16x8 af[4], bfr[4];
#pragma unroll
    for (int f = 0; f < 4; ++f) af[f] = *reinterpret_cast<const bf16x8*>(&As[wm + f * 16 + mr][kg]);
#pragma unroll
    for (int f = 0; f < 4; ++f) bfr[f] = *reinterpret_cast<const bf16x8*>(&Bs[wn + f * 16 + mr][kg]);
#pragma unroll
    for (int fi = 0; fi < 4; ++fi)
#pragma unroll
      for (int fj = 0; fj < 4; ++fj)
        acc[fi][fj] = __builtin_amdgcn_mfma_f32_16x16x32_bf16(af[fi], bfr[fj], acc[fi][fj], 0, 0, 0);
    __syncthreads();
  }

#pragma unroll
  for (int fi = 0; fi < 4; ++fi)
#pragma unroll
    for (int fj = 0; fj < 4; ++fj) {
      const int row0 = tm * 128 + wm + fi * 16 + (lane >> 4) * 4;
      const int col = tn * 128 + wn + fj * 16 + (lane & 15);
#pragma unroll
      for (int r = 0; r < 4; ++r) {
        const size_t row = (size_t)(row0 + r);
        float v = acc[fi][fj][r];
        if (MODE == 0 || MODE == 1) {
          gbuf[row * 3072 + col] = (__bf16)(v + bias[col]);
        } else if (MODE == 2) {
          float g = sigmoidf_(v + (float)gbuf[row * 3072 + col]);
          const size_t xrow = (size_t)(row & 31) * 512 + (row >> 5);
          if (col < 1024)
            gbuf[row * 3072 + col] = (__bf16)g;                                   // ud
          else
            gbuf[row * 3072 + col] = (__bf16)(g * xf[xrow * 1024 + (col - 1024)]); // rd*x
        } else {
          float hcd = tanhf_(v + (float)gbuf[row * 3072 + 2048 + col]);
          float ud = (float)gbuf[row * 3072 + col];
          const size_t xrow = (size_t)(row & 31) * 512 + (row >> 5);
          float xv = xf[xrow * 1024 + col];
          hout[xrow * 1024 + col] = xv + ud * (hcd - xv);
        }
      }
    }
}

// ---------------- persistent recurrence ----------------

// Barrier with NO cache-maintenance instructions: monotonic epoch counters,
// relaxed agent atomics only. Caller publishes data via agent atomics; the
// explicit s_waitcnt vmcnt(0) guarantees those pubs are committed at LIC
// before the leader's arrive-add (hand-rolled release without buffer_wbl2).
__device__ __forceinline__ void gbar(uint* bar, uint e) {
  asm volatile("s_waitcnt vmcnt(0)" ::: "memory");
  __syncthreads();
  if (threadIdx.x == 0) {
    uint* sub = bar + (blockIdx.x & 7) * 32;   // 8 sub-counters, 128B apart
    uint* top = bar + 256;
    uint* gen = bar + 288;
    uint old = __hip_atomic_fetch_add(sub, 1u, __ATOMIC_RELAXED, __HIP_MEMORY_SCOPE_AGENT);
    if (old + 1u == e * 8u) {
      uint o2 = __hip_atomic_fetch_add(top, 1u, __ATOMIC_RELAXED, __HIP_MEMORY_SCOPE_AGENT);
      if (o2 + 1u == e * 8u) {
        __hip_atomic_fetch_add(gen, 1u, __ATOMIC_RELAXED, __HIP_MEMORY_SCOPE_AGENT);
      }
    }
    while (__hip_atomic_load(gen, __ATOMIC_RELAXED, __HIP_MEMORY_SCOPE_AGENT) < e)
      __builtin_amdgcn_s_sleep(1);
  }
  __syncthreads();
}

// 64 WGs x 512 threads. WG b owns gg cols {16b..16b+15} u {1024+16b..} and hc cols {16b..16b+15}.
// Weights bf16 LDS-resident all 512 steps. Broadcast vectors (ht, r*ht) travel via LIC
// (8B agent atomics) straight into MFMA A-fragments — no LDS staging, no fences.
#define SMEM_BYTES 137984
#define WS 1032
__global__ __launch_bounds__(512) void recur_kernel(
    const __bf16* __restrict__ gates, const float* __restrict__ state,
    const __bf16* __restrict__ whtg_t, const __bf16* __restrict__ whtc_t,
    __bf16* __restrict__ ht_g, __bf16* __restrict__ rh_g,
    __bf16* __restrict__ htseq, float* __restrict__ otail, uint* __restrict__ bar) {
  extern __shared__ char smem[];
  __bf16* Wg  = (__bf16*)smem;                   // [32][WS]  66048 B
  __bf16* Wc  = (__bf16*)(smem + 66048);         // [16][WS]  33024 B
  float*  red = (float*)(smem + 99072);          // [8][32][33] 33792 B
  float*  u_s = (float*)(smem + 132864);         // [32][16]   2048 B
  float*  hp_s= (float*)(smem + 134912);         // [32][16]   2048 B (fp32 ht master, own cols)
  __bf16* p_s = (__bf16*)(smem + 136960);        // [32][16]   1024 B (pack buffer)

  const int b = blockIdx.x, tid = threadIdx.x;
  const int lane = tid & 63, w = tid >> 6;       // 8 waves; wave w owns K range [w*128, w*128+128)
  const int mr = lane & 15, kq = lane >> 4;
  const int k0 = w * 128;

  // ---- init: weights -> LDS ----
  for (int idx = tid; idx < 4096; idx += 512) {
    int row = idx >> 7, seg = idx & 127;
    int src = (row < 16) ? (b * 16 + row) : (1024 + b * 16 + row - 16);
    *reinterpret_cast<uint4*>(Wg + row * WS + seg * 8) =
        *reinterpret_cast<const uint4*>(whtg_t + (size_t)src * 1024 + seg * 8);
  }
  for (int idx = tid; idx < 2048; idx += 512) {
    int row = idx >> 7, seg = idx & 127;
    *reinterpret_cast<uint4*>(Wc + row * WS + seg * 8) =
        *reinterpret_cast<const uint4*>(whtc_t + (size_t)(b * 16 + row) * 1024 + seg * 8);
  }
  {
    int n = tid >> 4, cc = tid & 15;
    float sv = state[n * 1024 + b * 16 + cc];
    hp_s[n * 16 + cc] = sv;
    p_s[n * 16 + cc] = (__bf16)sv;
  }
  __syncthreads();
  if (tid < 128) {   // publish initial ht (own cols) via agent atomics
    int n = tid >> 2, c4 = tid & 3;
    ast(ht_g + n * 1024 + b * 16 + c4 * 4, *reinterpret_cast<u64*>(p_s + n * 16 + c4 * 4));
  }
  uint e = 1;
  gbar(bar, e);

  for (int t = 0; t < 512; ++t) {
    // ================= phase A: gg = sigmoid(gates + ht @ Whtg) =================
    {
      // prefetch this step's gate values (plain loads, L2-cached)
      float gpre0, gpre1;
      {
        int n = tid >> 5, col = tid & 31;
        int cc = (col < 16) ? (b * 16 + col) : (1024 + b * 16 + col - 16);
        gpre0 = (float)gates[(size_t)(t * 32 + n) * 3072 + cc];
        int o2 = tid + 512, n2 = o2 >> 5, col2 = o2 & 31;
        int cc2 = (col2 < 16) ? (b * 16 + col2) : (1024 + b * 16 + col2 - 16);
        gpre1 = (float)gates[(size_t)(t * 32 + n2) * 3072 + cc2];
      }
      // A-fragments straight from LIC
      B8 a0[4], a1[4];
#pragma unroll
      for (int c2 = 0; c2 < 4; ++c2) {
        int kb = k0 + c2 * 32 + kq * 8;
        a0[c2].u[0] = ald(ht_g + mr * 1024 + kb);
        a0[c2].u[1] = ald(ht_g + mr * 1024 + kb + 4);
        a1[c2].u[0] = ald(ht_g + (16 + mr) * 1024 + kb);
        a1[c2].u[1] = ald(ht_g + (16 + mr) * 1024 + kb + 4);
      }
      floatx4 acc[2][2] = {};
#pragma unroll
      for (int c2 = 0; c2 < 4; ++c2) {
        int kb = k0 + c2 * 32 + kq * 8;
        bf16x8 b0 = *reinterpret_cast<const bf16x8*>(Wg + mr * WS + kb);
        bf16x8 b1 = *reinterpret_cast<const bf16x8*>(Wg + (16 + mr) * WS + kb);
        acc[0][0] = __builtin_amdgcn_mfma_f32_16x16x32_bf16(a0[c2].v, b0, acc[0][0], 0, 0, 0);
        acc[0][1] = __builtin_amdgcn_mfma_f32_16x16x32_bf16(a0[c2].v, b1, acc[0][1], 0, 0, 0);
        acc[1][0] = __builtin_amdgcn_mfma_f32_16x16x32_bf16(a1[c2].v, b0, acc[1][0], 0, 0, 0);
        acc[1][1] = __builtin_amdgcn_mfma_f32_16x16x32_bf16(a1[c2].v, b1, acc[1][1], 0, 0, 0);
      }
#pragma unroll
      for (int ai = 0; ai < 2; ++ai)
#pragma unroll
        for (int cj = 0; cj < 2; ++cj)
#pragma unroll
          for (int r = 0; r < 4; ++r)
            red[w * 1056 + (ai * 16 + kq * 4 + r) * 33 + cj * 16 + mr] = acc[ai][cj][r];
      __syncthreads();
      // reduce over 8 waves; epilogue
#pragma unroll
      for (int h = 0; h < 2; ++h) {
        int o = tid + h * 512;
        int n = o >> 5, col = o & 31;
        float s = 0.f;
#pragma unroll
        for (int w8 = 0; w8 < 8; ++w8) s += red[w8 * 1056 + n * 33 + col];
        float gg = sigmoidf_(s + (h == 0 ? gpre0 : gpre1));
        if (col < 16) u_s[n * 16 + col] = gg;
        else p_s[n * 16 + (col - 16)] = (__bf16)(gg * hp_s[n * 16 + (col - 16)]);
      }
      __syncthreads();
      if (tid < 128) {   // publish r*ht slice
        int n = tid >> 2, c4 = tid & 3;
        ast(rh_g + n * 1024 + b * 16 + c4 * 4, *reinterpret_cast<u64*>(p_s + n * 16 + c4 * 4));
      }
    }
    gbar(bar, ++e);
    // ================= phase B: hc = tanh(gates_c + (r*ht) @ Whtc); update =================
    {
      float gcpre = 0.f;
      {
        int n = tid >> 4, col = tid & 15;
        gcpre = (float)gates[(size_t)(t * 32 + n) * 3072 + 2048 + b * 16 + col];
      }
      B8 a0[4], a1[4];
#pragma unroll
      for (int c2 = 0; c2 < 4; ++c2) {
        int kb = k0 + c2 * 32 + kq * 8;
        a0[c2].u[0] = ald(rh_g + mr * 1024 + kb);
        a0[c2].u[1] = ald(rh_g + mr * 1024 + kb + 4);
        a1[c2].u[0] = ald(rh_g + (16 + mr) * 1024 + kb);
        a1[c2].u[1] = ald(rh_g + (16 + mr) * 1024 + kb + 4);
      }
      floatx4 acc[2] = {};
#pragma unroll
      for (int c2 = 0; c2 < 4; ++c2) {
        int kb = k0 + c2 * 32 + kq * 8;
        bf16x8 bb = *reinterpret_cast<const bf16x8*>(Wc + mr * WS + kb);
        acc[0] = __builtin_amdgcn_mfma_f32_16x16x32_bf16(a0[c2].v, bb, acc[0], 0, 0, 0);
        acc[1] = __builtin_amdgcn_mfma_f32_16x16x32_bf16(a1[c2].v, bb, acc[1], 0, 0, 0);
      }
#pragma unroll
      for (int ai = 0; ai < 2; ++ai)
#pragma unroll
        for (int r = 0; r < 4; ++r)
          red[w * 1056 + (ai * 16 + kq * 4 + r) * 33 + mr] = acc[ai][r];
      __syncthreads();
      {
        int n = tid >> 4, col = tid & 15;
        float s = 0.f;
#pragma unroll
        for (int w8 = 0; w8 < 8; ++w8) s += red[w8 * 1056 + n * 33 + col];
        float hc = tanhf_(s + gcpre);
        float hp = hp_s[n * 16 + col];
        float uu = u_s[n * 16 + col];
        float hn = hp + uu * (hc - hp);
        hp_s[n * 16 + col] = hn;
        p_s[n * 16 + col] = (__bf16)hn;
        htseq[(size_t)(t * 32 + n) * 1024 + b * 16 + col] = (__bf16)hn;
        if (t == 511) otail[n * 1024 + b * 16 + col] = hn;
      }
      __syncthreads();
      if (tid < 128) {   // publish new ht slice
        int n = tid >> 2, c4 = tid & 3;
        ast(ht_g + n * 1024 + b * 16 + c4 * 4, *reinterpret_cast<u64*>(p_s + n * 16 + c4 * 4));
      }
    }
    gbar(bar, ++e);
  }
}

// ---------------- launch ----------------

extern "C" void kernel_launch(void* const* d_in, const int* in_sizes, int n_in,
                              void* d_out, int out_size, void* d_ws, size_t ws_size,
                              hipStream_t stream) {
  const float* x = (const float*)d_in[0];
  const float* state = (const float*)d_in[1];
  const float* weight = (const float*)d_in[2];
  const float* bias = (const float*)d_in[3];
  float* out = (float*)d_out;
  char* ws = (char*)d_ws;

  __bf16* gates  = (__bf16*)(ws + OFF_GATES);
  __bf16* xb     = (__bf16*)(ws + OFF_XB);
  __bf16* htseq  = (__bf16*)(ws + OFF_HTSEQ);
  __bf16* whtg_t = (__bf16*)(ws + OFF_WHTGT);
  __bf16* whtc_t = (__bf16*)(ws + OFF_WHTCT);
  __bf16* wxtt   = (__bf16*)(ws + OFF_WXTT);
  __bf16* whdt   = (__bf16*)(ws + OFF_WHDT);
  __bf16* wxd1t  = (__bf16*)(ws + OFF_WXD1T);
  __bf16* wxd2t  = (__bf16*)(ws + OFF_WXD2T);
  __bf16* ht_g   = (__bf16*)(ws + OFF_HTG);
  __bf16* rh_g   = (__bf16*)(ws + OFF_RHG);
  uint*   bar    = (uint*)(ws + OFF_BAR);

  // prep: x -> bf16 t-major (+ zero barrier), weight blocks -> bf16 B^T
  hipLaunchKernelGGL(convert_x, dim3(16384), dim3(256), 0, stream, (const float4*)x, xb, bar);
  hipLaunchKernelGGL(transpose_conv, dim3(96, 32), dim3(256), 0, stream, weight, wxtt);
  hipLaunchKernelGGL(transpose_conv, dim3(64, 32), dim3(256), 0, stream, weight + 3072, wxd1t);
  hipLaunchKernelGGL(transpose_conv, dim3(32, 32), dim3(256), 0, stream, weight + 5120, wxd2t);
  hipLaunchKernelGGL(transpose_conv, dim3(96, 32), dim3(256), 0, stream,
                     weight + (size_t)1024 * WLD + 3072, whdt);
  hipLaunchKernelGGL(transpose_conv, dim3(64, 32), dim3(256), 0, stream,
                     weight + (size_t)1024 * WLD, whtg_t);
  hipLaunchKernelGGL(transpose_conv, dim3(32, 32), dim3(256), 0, stream,
                     weight + (size_t)1024 * WLD + 2048, whtc_t);

  // gates = x @ Wxt + bias[:3H]   (t-major rows)
  hipLaunchKernelGGL((gemm_bt<0>), dim3(24, 128), dim3(256), 0, stream,
                     xb, 1024, wxtt, bias, gates, (const float*)nullptr, (float*)nullptr, 3072);

  // recurrence (cooperative, 64 WGs x 512 threads, 135KB dynamic LDS)
  {
    (void)hipFuncSetAttribute(reinterpret_cast<const void*>(recur_kernel),
                              hipFuncAttributeMaxDynamicSharedMemorySize, SMEM_BYTES);
    const __bf16* gatesc = gates;
    float* otail = out + 16777216;
    void* args[9];
    args[0] = (void*)&gatesc; args[1] = (void*)&state;  args[2] = (void*)&whtg_t;
    args[3] = (void*)&whtc_t; args[4] = (void*)&ht_g;   args[5] = (void*)&rh_g;
    args[6] = (void*)&htseq;  args[7] = (void*)&otail;  args[8] = (void*)&bar;
    hipLaunchCooperativeKernel(recur_kernel, dim3(64), dim3(512), args, SMEM_BYTES, stream);
  }

  // gd = ht_seq @ Whd + bias[3H:]  (into gates buffer)
  hipLaunchKernelGGL((gemm_bt<1>), dim3(24, 128), dim3(256), 0, stream,
                     htseq, 1024, whdt, bias + 3072, gates, (const float*)nullptr,
                     (float*)nullptr, 3072);
  // g2 = sigmoid(gd[:, :2D] + x @ Wxd[:, :2D]); ud/rx in-place
  hipLaunchKernelGGL((gemm_bt<2>), dim3(16, 128), dim3(256), 0, stream,
                     xb, 1024, wxd1t, bias, gates, x, (float*)nullptr, 2048);
  // hcd = tanh(gd[:, 2D:] + rx @ Wxd[:, 2D:]); h = x + ud*(hcd - x)
  hipLaunchKernelGGL((gemm_bt<3>), dim3(8, 128), dim3(256), 0, stream,
                     gates + 1024, 3072, wxd2t, bias, gates, x, out, 1024);
}

// Round 4
// 7114.496 us; speedup vs baseline: 12.0737x; 1.0307x over previous
//
#include <hip/hip_runtime.h>
#include <cstdint>
#include <cstddef>

typedef unsigned int uint;
typedef unsigned long long u64;
typedef __attribute__((ext_vector_type(8))) __bf16 bf16x8;
typedef __attribute__((ext_vector_type(4))) __bf16 bf16x4v;
typedef __attribute__((ext_vector_type(4))) float floatx4;

#define WLD 6144      // weight row stride = 3*(D+H)

// ---- workspace layout (bytes). Row convention for xb/gates/htseq: r = t*32 + n (t-major).
static const size_t OFF_GATES = 0;              // bf16 16384x3072
static const size_t OFF_XB    = 100663296;      // bf16 16384x1024
static const size_t OFF_HTSEQ = 134217728;      // bf16 16384x1024
// whtg_t/whtc_t overlay the htseq region: consumed (into LDS) before any htseq write.
static const size_t OFF_WHTGT = OFF_HTSEQ;              // bf16 2048x1024
static const size_t OFF_WHTCT = OFF_HTSEQ + 4194304;    // bf16 1024x1024
static const size_t OFF_WXTT  = 167772160;      // bf16 3072x1024 (B^T)
static const size_t OFF_WHDT  = 174063616;      // bf16 3072x1024
static const size_t OFF_WXD1T = 180355072;      // bf16 2048x1024
static const size_t OFF_WXD2T = 184549376;      // bf16 1024x1024
static const size_t OFF_HTG   = 186646528;      // bf16 32x1024 (ht broadcast, LIC-coherent)
static const size_t OFF_RHG   = 186712064;      // bf16 32x1024 (r*ht broadcast)
static const size_t OFF_BAR   = 186777600;      // uint[512]

__device__ __forceinline__ float sigmoidf_(float x) { return 1.f / (1.f + __expf(-x)); }
__device__ __forceinline__ float tanhf_(float x) { float e = __expf(2.f * x); return 1.f - 2.f / (e + 1.f); }

// agent-scope relaxed atomics: operate at LIC (device coherence point),
// no buffer_wbl2 / buffer_inv emitted.
__device__ __forceinline__ u64 ald(const __bf16* p) {
  return __hip_atomic_load((const u64*)p, __ATOMIC_RELAXED, __HIP_MEMORY_SCOPE_AGENT);
}
__device__ __forceinline__ void ast(__bf16* p, u64 v) {
  __hip_atomic_store((u64*)p, v, __ATOMIC_RELAXED, __HIP_MEMORY_SCOPE_AGENT);
}
union B8 { u64 u[2]; bf16x8 v; };

// ---------------- prep kernels ----------------

// x [n][t][1024] fp32 -> xb bf16 rows r=t*32+n. Also zeroes barrier state (atomically,
// so the zeros live at the coherence point).
__global__ __launch_bounds__(256) void convert_x(const float4* __restrict__ x4,
                                                 __bf16* __restrict__ xb,
                                                 uint* __restrict__ bar) {
  if (blockIdx.x == 0) {
    __hip_atomic_store(bar + threadIdx.x, 0u, __ATOMIC_RELAXED, __HIP_MEMORY_SCOPE_AGENT);
    __hip_atomic_store(bar + 256 + threadIdx.x, 0u, __ATOMIC_RELAXED, __HIP_MEMORY_SCOPE_AGENT);
  }
  const int s = blockIdx.x;              // source row n*512+t
  const int n = s >> 9, t = s & 511;
  const int d = (t << 5) | n;            // dest row t*32+n
  float4 v = x4[(size_t)s * 256 + threadIdx.x];
  bf16x4v o = { (__bf16)v.x, (__bf16)v.y, (__bf16)v.z, (__bf16)v.w };
  *reinterpret_cast<bf16x4v*>(xb + (size_t)d * 1024 + threadIdx.x * 4) = o;
}

// src: fp32 block, row stride WLD, 1024 rows (k), gridDim.x*32 cols. dst: bf16 [c][k].
__global__ __launch_bounds__(256) void transpose_conv(const float* __restrict__ src,
                                                      __bf16* __restrict__ dst) {
  __shared__ float t[32][33];
  const int ct = blockIdx.x, kt = blockIdx.y;
  const int j = threadIdx.x & 31, ig = threadIdx.x >> 5;
#pragma unroll
  for (int ii = 0; ii < 4; ++ii) {
    int i = ig * 4 + ii;
    t[i][j] = src[(size_t)(kt * 32 + i) * WLD + ct * 32 + j];
  }
  __syncthreads();
#pragma unroll
  for (int ii = 0; ii < 4; ++ii) {
    int cc = ig * 4 + ii;
    dst[(size_t)(ct * 32 + cc) * 1024 + kt * 32 + j] = (__bf16)t[j][cc];
  }
}

// ---------------- MFMA GEMM (A row-major bf16 t-major rows, B^T bf16 [n][k]) ----------------
template <int MODE>
__global__ __launch_bounds__(256) void gemm_bt(const __bf16* __restrict__ A, int lda,
                                               const __bf16* __restrict__ BT,
                                               const float* __restrict__ bias,
                                               __bf16* __restrict__ gbuf,
                                               const float* __restrict__ xf,
                                               float* __restrict__ hout, int ncols) {
  __shared__ __bf16 As[128][48];
  __shared__ __bf16 Bs[128][48];
  const int tid = threadIdx.x;
  const int lane = tid & 63, wave = tid >> 6;
  const int tm = blockIdx.y, tn = blockIdx.x;
  const int wm = (wave & 1) * 64, wn = (wave >> 1) * 64;
  floatx4 acc[4][4] = {};
  const int c = tid & 3, r0 = tid >> 2;
  const size_t arow = (size_t)tm * 128;
  const size_t brow = (size_t)tn * 128;

  for (int kk = 0; kk < 1024; kk += 32) {
    *reinterpret_cast<uint4*>(&As[r0][c * 8]) =
        *reinterpret_cast<const uint4*>(A + (arow + r0) * (size_t)lda + kk + c * 8);
    *reinterpret_cast<uint4*>(&As[r0 + 64][c * 8]) =
        *reinterpret_cast<const uint4*>(A + (arow + r0 + 64) * (size_t)lda + kk + c * 8);
    *reinterpret_cast<uint4*>(&Bs[r0][c * 8]) =
        *reinterpret_cast<const uint4*>(BT + (brow + r0) * 1024 + kk + c * 8);
    *reinterpret_cast<uint4*>(&Bs[r0 + 64][c * 8]) =
        *reinterpret_cast<const uint4*>(BT + (brow + r0 + 64) * 1024 + kk + c * 8);
    __syncthreads();
    const int mr = lane & 15, kg = (lane >> 4) * 8;
    bf16x8 af[4], bfr[4];
#pragma unroll
    for (int f = 0; f < 4; ++f) af[f] = *reinterpret_cast<const bf16x8*>(&As[wm + f * 16 + mr][kg]);
#pragma unroll
    for (int f = 0; f < 4; ++f) bfr[f] = *reinterpret_cast<const bf16x8*>(&Bs[wn + f * 16 + mr][kg]);
#pragma unroll
    for (int fi = 0; fi < 4; ++fi)
#pragma unroll
      for (int fj = 0; fj < 4; ++fj)
        acc[fi][fj] = __builtin_amdgcn_mfma_f32_16x16x32_bf16(af[fi], bfr[fj], acc[fi][fj], 0, 0, 0);
    __syncthreads();
  }

#pragma unroll
  for (int fi = 0; fi < 4; ++fi)
#pragma unroll
    for (int fj = 0; fj < 4; ++fj) {
      const int row0 = tm * 128 + wm + fi * 16 + (lane >> 4) * 4;
      const int col = tn * 128 + wn + fj * 16 + (lane & 15);
#pragma unroll
      for (int r = 0; r < 4; ++r) {
        const size_t row = (size_t)(row0 + r);
        float v = acc[fi][fj][r];
        if (MODE == 0 || MODE == 1) {
          gbuf[row * 3072 + col] = (__bf16)(v + bias[col]);
        } else if (MODE == 2) {
          float g = sigmoidf_(v + (float)gbuf[row * 3072 + col]);
          const size_t xrow = (size_t)(row & 31) * 512 + (row >> 5);
          if (col < 1024)
            gbuf[row * 3072 + col] = (__bf16)g;                                   // ud
          else
            gbuf[row * 3072 + col] = (__bf16)(g * xf[xrow * 1024 + (col - 1024)]); // rd*x
        } else {
          float hcd = tanhf_(v + (float)gbuf[row * 3072 + 2048 + col]);
          float ud = (float)gbuf[row * 3072 + col];
          const size_t xrow = (size_t)(row & 31) * 512 + (row >> 5);
          float xv = xf[xrow * 1024 + col];
          hout[xrow * 1024 + col] = xv + ud * (hcd - xv);
        }
      }
    }
}

// ---------------- persistent recurrence ----------------

// Single-RT barrier wait: wave 0 lane 0 polls the flat LIC counter (monotonic,
// +64 per barrier); other waves spin on an LDS epoch flag. No cache maintenance.
__device__ __forceinline__ void gwait(uint* bar, uint e, volatile uint* lflag, int tid) {
  if (tid == 0) {
    while ((int)(__hip_atomic_load(bar, __ATOMIC_RELAXED, __HIP_MEMORY_SCOPE_AGENT) - 64u * e) < 0) {}
    lflag[0] = e;
  } else if ((tid & 63) == 0) {
    while ((int)(lflag[0] - e) < 0) {}
  }
  // lanes of each wave are released in lockstep with their lane 0
}

// 64 WGs x 512 threads. WG b owns gg cols {16b..16b+15} u {1024+16b..} and hc cols {16b..16b+15}.
// Weights bf16 LDS-resident all 512 steps. Broadcast vectors (ht, r*ht) travel via LIC
// (8B agent atomics) straight into MFMA A-fragments. Publish+arrive by wave 0 only.
#define SMEM_BYTES 138048
#define WS 1032
__global__ __launch_bounds__(512) void recur_kernel(
    const __bf16* __restrict__ gates, const float* __restrict__ state,
    const __bf16* __restrict__ whtg_t, const __bf16* __restrict__ whtc_t,
    __bf16* __restrict__ ht_g, __bf16* __restrict__ rh_g,
    __bf16* __restrict__ htseq, float* __restrict__ otail, uint* __restrict__ bar) {
  extern __shared__ char smem[];
  __bf16* Wg  = (__bf16*)smem;                   // [32][WS]  66048 B
  __bf16* Wc  = (__bf16*)(smem + 66048);         // [16][WS]  33024 B
  float*  red = (float*)(smem + 99072);          // [8][32][33] 33792 B
  float*  u_s = (float*)(smem + 132864);         // [32][16]   2048 B
  float*  hp_s= (float*)(smem + 134912);         // [32][16]   2048 B (fp32 ht master, own cols)
  __bf16* p_s = (__bf16*)(smem + 136960);        // [32][16]   1024 B (pack buffer)
  volatile uint* lflag = (volatile uint*)(smem + 137984);

  const int b = blockIdx.x, tid = threadIdx.x;
  const int lane = tid & 63, w = tid >> 6;       // 8 waves; wave w owns K range [w*128, w*128+128)
  const int mr = lane & 15, kq = lane >> 4;
  const int k0 = w * 128;

  // ---- init: weights -> LDS ----
  for (int idx = tid; idx < 4096; idx += 512) {
    int row = idx >> 7, seg = idx & 127;
    int src = (row < 16) ? (b * 16 + row) : (1024 + b * 16 + row - 16);
    *reinterpret_cast<uint4*>(Wg + row * WS + seg * 8) =
        *reinterpret_cast<const uint4*>(whtg_t + (size_t)src * 1024 + seg * 8);
  }
  for (int idx = tid; idx < 2048; idx += 512) {
    int row = idx >> 7, seg = idx & 127;
    *reinterpret_cast<uint4*>(Wc + row * WS + seg * 8) =
        *reinterpret_cast<const uint4*>(whtc_t + (size_t)(b * 16 + row) * 1024 + seg * 8);
  }
  {
    int n = tid >> 4, cc = tid & 15;
    float sv = state[n * 1024 + b * 16 + cc];
    hp_s[n * 16 + cc] = sv;
    p_s[n * 16 + cc] = (__bf16)sv;
    if (tid == 0) lflag[0] = 0;
  }
  __syncthreads();
  if (tid < 64) {   // wave 0: publish initial ht, drain, arrive
    u64* ps64 = (u64*)p_s;
    int i0 = tid, i1 = tid + 64;
    ast(ht_g + (i0 >> 2) * 1024 + b * 16 + (i0 & 3) * 4, ps64[i0]);
    ast(ht_g + (i1 >> 2) * 1024 + b * 16 + (i1 & 3) * 4, ps64[i1]);
    asm volatile("s_waitcnt vmcnt(0)" ::: "memory");
    if (tid == 0)
      (void)__hip_atomic_fetch_add(bar, 1u, __ATOMIC_RELAXED, __HIP_MEMORY_SCOPE_AGENT);
  }
  uint e = 1;

  for (int t = 0; t < 512; ++t) {
    // ================= phase A: gg = sigmoid(gates + ht @ Whtg) =================
    {
      // prefetch gates (off the post-barrier critical path)
      __bf16 graw0, graw1;
      {
        int n = tid >> 5, col = tid & 31;
        int cc = (col < 16) ? (b * 16 + col) : (1024 + b * 16 + col - 16);
        graw0 = gates[(size_t)(t * 32 + n) * 3072 + cc];
        int o2 = tid + 512, n2 = o2 >> 5, col2 = o2 & 31;
        int cc2 = (col2 < 16) ? (b * 16 + col2) : (1024 + b * 16 + col2 - 16);
        graw1 = gates[(size_t)(t * 32 + n2) * 3072 + cc2];
      }
      gwait(bar, e, lflag, tid);
      // A-fragments straight from LIC
      B8 a0[4], a1[4];
#pragma unroll
      for (int c2 = 0; c2 < 4; ++c2) {
        int kb = k0 + c2 * 32 + kq * 8;
        a0[c2].u[0] = ald(ht_g + mr * 1024 + kb);
        a0[c2].u[1] = ald(ht_g + mr * 1024 + kb + 4);
        a1[c2].u[0] = ald(ht_g + (16 + mr) * 1024 + kb);
        a1[c2].u[1] = ald(ht_g + (16 + mr) * 1024 + kb + 4);
      }
      floatx4 acc[2][2] = {};
#pragma unroll
      for (int c2 = 0; c2 < 4; ++c2) {
        int kb = k0 + c2 * 32 + kq * 8;
        bf16x8 b0 = *reinterpret_cast<const bf16x8*>(Wg + mr * WS + kb);
        bf16x8 b1 = *reinterpret_cast<const bf16x8*>(Wg + (16 + mr) * WS + kb);
        acc[0][0] = __builtin_amdgcn_mfma_f32_16x16x32_bf16(a0[c2].v, b0, acc[0][0], 0, 0, 0);
        acc[0][1] = __builtin_amdgcn_mfma_f32_16x16x32_bf16(a0[c2].v, b1, acc[0][1], 0, 0, 0);
        acc[1][0] = __builtin_amdgcn_mfma_f32_16x16x32_bf16(a1[c2].v, b0, acc[1][0], 0, 0, 0);
        acc[1][1] = __builtin_amdgcn_mfma_f32_16x16x32_bf16(a1[c2].v, b1, acc[1][1], 0, 0, 0);
      }
#pragma unroll
      for (int ai = 0; ai < 2; ++ai)
#pragma unroll
        for (int cj = 0; cj < 2; ++cj)
#pragma unroll
          for (int r = 0; r < 4; ++r)
            red[w * 1056 + (ai * 16 + kq * 4 + r) * 33 + cj * 16 + mr] = acc[ai][cj][r];
      __syncthreads();
      // reduce over 8 waves; epilogue
      {
        int n = tid >> 5, col = tid & 31;
        float s = 0.f;
#pragma unroll
        for (int w8 = 0; w8 < 8; ++w8) s += red[w8 * 1056 + n * 33 + col];
        float gg = sigmoidf_(s + (float)graw0);
        if (col < 16) u_s[n * 16 + col] = gg;
        else p_s[n * 16 + (col - 16)] = (__bf16)(gg * hp_s[n * 16 + (col - 16)]);
        int o2 = tid + 512, n2 = o2 >> 5, col2 = o2 & 31;
        float s2 = 0.f;
#pragma unroll
        for (int w8 = 0; w8 < 8; ++w8) s2 += red[w8 * 1056 + n2 * 33 + col2];
        float gg2 = sigmoidf_(s2 + (float)graw1);
        if (col2 < 16) u_s[n2 * 16 + col2] = gg2;
        else p_s[n2 * 16 + (col2 - 16)] = (__bf16)(gg2 * hp_s[n2 * 16 + (col2 - 16)]);
      }
      __syncthreads();
      if (tid < 64) {   // wave 0: publish r*ht, drain, arrive
        u64* ps64 = (u64*)p_s;
        int i0 = tid, i1 = tid + 64;
        ast(rh_g + (i0 >> 2) * 1024 + b * 16 + (i0 & 3) * 4, ps64[i0]);
        ast(rh_g + (i1 >> 2) * 1024 + b * 16 + (i1 & 3) * 4, ps64[i1]);
        asm volatile("s_waitcnt vmcnt(0)" ::: "memory");
        if (tid == 0)
          (void)__hip_atomic_fetch_add(bar, 1u, __ATOMIC_RELAXED, __HIP_MEMORY_SCOPE_AGENT);
      }
    }
    // ================= phase B: hc = tanh(gates_c + (r*ht) @ Whtc); update =================
    {
      __bf16 gcraw;
      {
        int n = tid >> 4, col = tid & 15;
        gcraw = gates[(size_t)(t * 32 + n) * 3072 + 2048 + b * 16 + col];
      }
      gwait(bar, e + 1, lflag, tid);
      B8 a0[4], a1[4];
#pragma unroll
      for (int c2 = 0; c2 < 4; ++c2) {
        int kb = k0 + c2 * 32 + kq * 8;
        a0[c2].u[0] = ald(rh_g + mr * 1024 + kb);
        a0[c2].u[1] = ald(rh_g + mr * 1024 + kb + 4);
        a1[c2].u[0] = ald(rh_g + (16 + mr) * 1024 + kb);
        a1[c2].u[1] = ald(rh_g + (16 + mr) * 1024 + kb + 4);
      }
      floatx4 acc[2] = {};
#pragma unroll
      for (int c2 = 0; c2 < 4; ++c2) {
        int kb = k0 + c2 * 32 + kq * 8;
        bf16x8 bb = *reinterpret_cast<const bf16x8*>(Wc + mr * WS + kb);
        acc[0] = __builtin_amdgcn_mfma_f32_16x16x32_bf16(a0[c2].v, bb, acc[0], 0, 0, 0);
        acc[1] = __builtin_amdgcn_mfma_f32_16x16x32_bf16(a1[c2].v, bb, acc[1], 0, 0, 0);
      }
#pragma unroll
      for (int ai = 0; ai < 2; ++ai)
#pragma unroll
        for (int r = 0; r < 4; ++r)
          red[w * 1056 + (ai * 16 + kq * 4 + r) * 33 + mr] = acc[ai][r];
      __syncthreads();
      {
        int n = tid >> 4, col = tid & 15;
        float s = 0.f;
#pragma unroll
        for (int w8 = 0; w8 < 8; ++w8) s += red[w8 * 1056 + n * 33 + col];
        float hc = tanhf_(s + (float)gcraw);
        float hp = hp_s[n * 16 + col];
        float uu = u_s[n * 16 + col];
        float hn = hp + uu * (hc - hp);
        hp_s[n * 16 + col] = hn;
        p_s[n * 16 + col] = (__bf16)hn;
        htseq[(size_t)(t * 32 + n) * 1024 + b * 16 + col] = (__bf16)hn;
        if (t == 511) otail[n * 1024 + b * 16 + col] = hn;
      }
      __syncthreads();
      if (tid < 64) {   // wave 0: publish new ht, drain, arrive
        u64* ps64 = (u64*)p_s;
        int i0 = tid, i1 = tid + 64;
        ast(ht_g + (i0 >> 2) * 1024 + b * 16 + (i0 & 3) * 4, ps64[i0]);
        ast(ht_g + (i1 >> 2) * 1024 + b * 16 + (i1 & 3) * 4, ps64[i1]);
        asm volatile("s_waitcnt vmcnt(0)" ::: "memory");
        if (tid == 0)
          (void)__hip_atomic_fetch_add(bar, 1u, __ATOMIC_RELAXED, __HIP_MEMORY_SCOPE_AGENT);
      }
    }
    e += 2;
  }
}

// ---------------- launch ----------------

extern "C" void kernel_launch(void* const* d_in, const int* in_sizes, int n_in,
                              void* d_out, int out_size, void* d_ws, size_t ws_size,
                              hipStream_t stream) {
  const float* x = (const float*)d_in[0];
  const float* state = (const float*)d_in[1];
  const float* weight = (const float*)d_in[2];
  const float* bias = (const float*)d_in[3];
  float* out = (float*)d_out;
  char* ws = (char*)d_ws;

  __bf16* gates  = (__bf16*)(ws + OFF_GATES);
  __bf16* xb     = (__bf16*)(ws + OFF_XB);
  __bf16* htseq  = (__bf16*)(ws + OFF_HTSEQ);
  __bf16* whtg_t = (__bf16*)(ws + OFF_WHTGT);
  __bf16* whtc_t = (__bf16*)(ws + OFF_WHTCT);
  __bf16* wxtt   = (__bf16*)(ws + OFF_WXTT);
  __bf16* whdt   = (__bf16*)(ws + OFF_WHDT);
  __bf16* wxd1t  = (__bf16*)(ws + OFF_WXD1T);
  __bf16* wxd2t  = (__bf16*)(ws + OFF_WXD2T);
  __bf16* ht_g   = (__bf16*)(ws + OFF_HTG);
  __bf16* rh_g   = (__bf16*)(ws + OFF_RHG);
  uint*   bar    = (uint*)(ws + OFF_BAR);

  // prep: x -> bf16 t-major (+ zero barrier), weight blocks -> bf16 B^T
  hipLaunchKernelGGL(convert_x, dim3(16384), dim3(256), 0, stream, (const float4*)x, xb, bar);
  hipLaunchKernelGGL(transpose_conv, dim3(96, 32), dim3(256), 0, stream, weight, wxtt);
  hipLaunchKernelGGL(transpose_conv, dim3(64, 32), dim3(256), 0, stream, weight + 3072, wxd1t);
  hipLaunchKernelGGL(transpose_conv, dim3(32, 32), dim3(256), 0, stream, weight + 5120, wxd2t);
  hipLaunchKernelGGL(transpose_conv, dim3(96, 32), dim3(256), 0, stream,
                     weight + (size_t)1024 * WLD + 3072, whdt);
  hipLaunchKernelGGL(transpose_conv, dim3(64, 32), dim3(256), 0, stream,
                     weight + (size_t)1024 * WLD, whtg_t);
  hipLaunchKernelGGL(transpose_conv, dim3(32, 32), dim3(256), 0, stream,
                     weight + (size_t)1024 * WLD + 2048, whtc_t);

  // gates = x @ Wxt + bias[:3H]   (t-major rows)
  hipLaunchKernelGGL((gemm_bt<0>), dim3(24, 128), dim3(256), 0, stream,
                     xb, 1024, wxtt, bias, gates, (const float*)nullptr, (float*)nullptr, 3072);

  // recurrence (cooperative, 64 WGs x 512 threads, 135KB dynamic LDS)
  {
    (void)hipFuncSetAttribute(reinterpret_cast<const void*>(recur_kernel),
                              hipFuncAttributeMaxDynamicSharedMemorySize, SMEM_BYTES);
    const __bf16* gatesc = gates;
    float* otail = out + 16777216;
    void* args[9];
    args[0] = (void*)&gatesc; args[1] = (void*)&state;  args[2] = (void*)&whtg_t;
    args[3] = (void*)&whtc_t; args[4] = (void*)&ht_g;   args[5] = (void*)&rh_g;
    args[6] = (void*)&htseq;  args[7] = (void*)&otail;  args[8] = (void*)&bar;
    hipLaunchCooperativeKernel(recur_kernel, dim3(64), dim3(512), args, SMEM_BYTES, stream);
  }

  // gd = ht_seq @ Whd + bias[3H:]  (into gates buffer)
  hipLaunchKernelGGL((gemm_bt<1>), dim3(24, 128), dim3(256), 0, stream,
                     htseq, 1024, whdt, bias + 3072, gates, (const float*)nullptr,
                     (float*)nullptr, 3072);
  // g2 = sigmoid(gd[:, :2D] + x @ Wxd[:, :2D]); ud/rx in-place
  hipLaunchKernelGGL((gemm_bt<2>), dim3(16, 128), dim3(256), 0, stream,
                     xb, 1024, wxd1t, bias, gates, x, (float*)nullptr, 2048);
  // hcd = tanh(gd[:, 2D:] + rx @ Wxd[:, 2D:]); h = x + ud*(hcd - x)
  hipLaunchKernelGGL((gemm_bt<3>), dim3(8, 128), dim3(256), 0, stream,
                     gates + 1024, 3072, wxd2t, bias, gates, x, out, 1024);
}